// Round 1
// baseline (508.820 us; speedup 1.0000x reference)
//
#include <hip/hip_runtime.h>
#include <hip/hip_bf16.h>
#include <math.h>

// Problem constants (B=2, T=4096, D=2048, H=2048, W=4)
#define B_DIM 2
#define T_DIM 4096
#define D_DIM 2048
#define H_DIM 2048
#define W_K   4
#define M_DIM (B_DIM * T_DIM)   // 8192 rows (tokens)
#define N2_DIM (D_DIM * W_K)    // 8192 (flat kernel cols)

typedef __bf16 bf16x8 __attribute__((ext_vector_type(8)));
typedef float  f32x4  __attribute__((ext_vector_type(4)));

#define BM 128
#define BN 128
#define BK 32

__device__ __forceinline__ unsigned short f2bf(float f) {
    unsigned int u = __float_as_uint(f);
    unsigned int r = (u + 0x7FFFu + ((u >> 16) & 1u)) >> 16;  // RNE
    return (unsigned short)r;
}

__device__ __forceinline__ float silu_f(float v) {
    return v / (1.0f + __expf(-v));
}

// fp32 -> bf16-bits conversion, vectorized x4
__global__ void cvt_f32_to_bf16(const float* __restrict__ in,
                                unsigned short* __restrict__ out, int n4) {
    int i = blockIdx.x * blockDim.x + threadIdx.x;
    if (i >= n4) return;
    float4 v = reinterpret_cast<const float4*>(in)[i];
    ushort4 o;
    o.x = f2bf(v.x); o.y = f2bf(v.y); o.z = f2bf(v.z); o.w = f2bf(v.w);
    reinterpret_cast<ushort4*>(out)[i] = o;
}

// NT GEMM: C[M,N] = A[M,K] * Bm[N,K]^T, bf16 inputs, fp32 accumulate.
// EPI=0: Hout[row,col] = bf16(silu(C))            (kernel-generator layer 1)
// EPI=1: fused bias + dynamic causal conv + silu  (layer 2 + conv)
template <int EPI>
__global__ __launch_bounds__(256, 2)
void gemm_nt(const unsigned short* __restrict__ A,
             const unsigned short* __restrict__ Bm,
             int M, int N, int K,
             unsigned short* __restrict__ Hout,
             const float* __restrict__ bias,
             const float* __restrict__ Xf,
             float* __restrict__ Out) {
    const int tid  = threadIdx.x;
    const int wave = tid >> 6;
    const int lane = tid & 63;
    const int wr   = wave >> 1;   // wave row (0..1)
    const int wc   = wave & 1;    // wave col (0..1)
    const int m0 = blockIdx.y * BM;
    const int n0 = blockIdx.x * BN;

    __shared__ __align__(16) unsigned short sA[2][BM * BK];
    __shared__ __align__(16) unsigned short sB[2][BN * BK];

    f32x4 acc[4][4];
#pragma unroll
    for (int i = 0; i < 4; ++i)
#pragma unroll
        for (int j = 0; j < 4; ++j) acc[i][j] = (f32x4)0.0f;

    const int srow = lane >> 2;        // 0..15 within a 16-row chunk
    const int scol = (lane & 3) * 8;   // k-offset in elements

    // Stage one BK-slice of A and B tiles into LDS via async global->LDS.
    // LDS dest is wave-uniform base; HW scatters lane l at base + l*16B,
    // which matches row-major [chunk of 16 rows][BK] exactly.
    auto stage = [&](int buf, int ko) {
#pragma unroll
        for (int call = 0; call < 2; ++call) {
            int ci = call * 4 + wave;          // chunk 0..7 (16 rows each)
            int r  = ci * 16 + srow;
            const unsigned short* ga = &A[(size_t)(m0 + r) * K + ko + scol];
            const unsigned short* gb = &Bm[(size_t)(n0 + r) * K + ko + scol];
            __builtin_amdgcn_global_load_lds(
                (const __attribute__((address_space(1))) void*)ga,
                (__attribute__((address_space(3))) void*)&sA[buf][ci * 512],
                16, 0, 0);
            __builtin_amdgcn_global_load_lds(
                (const __attribute__((address_space(1))) void*)gb,
                (__attribute__((address_space(3))) void*)&sB[buf][ci * 512],
                16, 0, 0);
        }
    };

    stage(0, 0);
    asm volatile("s_waitcnt vmcnt(0)" ::: "memory");
    __syncthreads();

    // A/B fragment LDS element offsets (16x16x32 bf16 layout):
    // lane holds row (lane&15), k = (lane>>4)*8 .. +7  -> contiguous 16B
    const int aoff = (wr * 64 + (lane & 15)) * BK + (lane >> 4) * 8;
    const int boff = (wc * 64 + (lane & 15)) * BK + (lane >> 4) * 8;

    int cur = 0;
    const int nk = K / BK;
    for (int kt = 0; kt < nk; ++kt) {
        if (kt + 1 < nk) stage(cur ^ 1, (kt + 1) * BK);

        bf16x8 af[4], bfr[4];
#pragma unroll
        for (int i = 0; i < 4; ++i) {
            af[i]  = *reinterpret_cast<const bf16x8*>(&sA[cur][aoff + i * 16 * BK]);
            bfr[i] = *reinterpret_cast<const bf16x8*>(&sB[cur][boff + i * 16 * BK]);
        }
#pragma unroll
        for (int i = 0; i < 4; ++i)
#pragma unroll
            for (int j = 0; j < 4; ++j)
                acc[i][j] = __builtin_amdgcn_mfma_f32_16x16x32_bf16(
                    af[i], bfr[j], acc[i][j], 0, 0, 0);

        asm volatile("s_waitcnt vmcnt(0)" ::: "memory");
        __syncthreads();
        cur ^= 1;
    }

    if (EPI == 0) {
        // h = silu(C) -> bf16 [M, N]
#pragma unroll
        for (int i = 0; i < 4; ++i) {
            int rowb = m0 + wr * 64 + i * 16 + (lane >> 4) * 4;
#pragma unroll
            for (int j = 0; j < 4; ++j) {
                int col = n0 + wc * 64 + j * 16 + (lane & 15);
#pragma unroll
                for (int r = 0; r < 4; ++r) {
                    float v = acc[i][j][r];
                    Hout[(size_t)(rowb + r) * N + col] = f2bf(silu_f(v));
                }
            }
        }
    } else {
        // Fused: k = C + bias; out[b,t,d] = silu(sum_w x[b,t-3+w,d] * k[.., d*4+w])
        // col -> (d = col>>2, w = col&3); 4-lane butterfly sums over w.
#pragma unroll
        for (int i = 0; i < 4; ++i) {
            int rowb = m0 + wr * 64 + i * 16 + (lane >> 4) * 4;
#pragma unroll
            for (int j = 0; j < 4; ++j) {
                int col = n0 + wc * 64 + j * 16 + (lane & 15);
                int d = col >> 2;
                int w = col & 3;
                float bv = bias[col];
#pragma unroll
                for (int r = 0; r < 4; ++r) {
                    int row = rowb + r;
                    int b = row >> 12;            // T = 4096
                    int t = row & (T_DIM - 1);
                    float v = acc[i][j][r] + bv;
                    int ts = t - (W_K - 1) + w;   // causal window
                    float xv = (ts >= 0) ? Xf[((size_t)b * T_DIM + ts) * D_DIM + d]
                                         : 0.0f;
                    float p = v * xv;
                    p += __shfl_xor(p, 1);
                    p += __shfl_xor(p, 2);
                    if ((lane & 3) == 0) {
                        Out[((size_t)b * T_DIM + t) * D_DIM + d] = silu_f(p);
                    }
                }
            }
        }
    }
}

extern "C" void kernel_launch(void* const* d_in, const int* in_sizes, int n_in,
                              void* d_out, int out_size, void* d_ws, size_t ws_size,
                              hipStream_t stream) {
    const float* x    = (const float*)d_in[0];  // [B,T,D]
    const float* w1   = (const float*)d_in[1];  // [H,D]
    const float* w2w  = (const float*)d_in[2];  // [D*W,H]
    const float* w2b  = (const float*)d_in[3];  // [D*W]
    float* out = (float*)d_out;

    // Workspace layout (75.5 MB total, xb region reused for w2b after GEMM1):
    //   ws0: xb [M,D] bf16 (33.5MB), later w2wb [N2,H] bf16 (33.5MB)
    //   ws1: w1b [H,D] bf16 (8.4MB)
    //   ws2: hb  [M,H] bf16 (33.5MB)
    unsigned short* ws0 = (unsigned short*)d_ws;
    unsigned short* ws1 = ws0 + (size_t)M_DIM * D_DIM;
    unsigned short* ws2 = ws1 + (size_t)H_DIM * D_DIM;

    const int CT = 256;
    {
        int n4 = (M_DIM * D_DIM) / 4;
        cvt_f32_to_bf16<<<(n4 + CT - 1) / CT, CT, 0, stream>>>(x, ws0, n4);
    }
    {
        int n4 = (H_DIM * D_DIM) / 4;
        cvt_f32_to_bf16<<<(n4 + CT - 1) / CT, CT, 0, stream>>>(w1, ws1, n4);
    }
    // GEMM1: hb = silu(xb @ w1b^T)  [8192, 2048]
    gemm_nt<0><<<dim3(H_DIM / BN, M_DIM / BM), 256, 0, stream>>>(
        ws0, ws1, M_DIM, H_DIM, D_DIM, ws2, nullptr, nullptr, nullptr);
    // convert w2_w into ws0 (xb now dead)
    {
        int n4 = (N2_DIM * H_DIM) / 4;
        cvt_f32_to_bf16<<<(n4 + CT - 1) / CT, CT, 0, stream>>>(w2w, ws0, n4);
    }
    // GEMM2 + fused bias/conv/silu -> out
    gemm_nt<1><<<dim3(N2_DIM / BN, M_DIM / BM), 256, 0, stream>>>(
        ws2, ws0, M_DIM, N2_DIM, H_DIM, nullptr, w2b, x, out);
}